// Round 9
// baseline (1969.789 us; speedup 1.0000x reference)
//
#include <hip/hip_runtime.h>
#include <type_traits>
#include <utility>

typedef _Float16 f16;
typedef f16 f16x4 __attribute__((ext_vector_type(4)));
typedef f16 f16x8 __attribute__((ext_vector_type(8)));
typedef float f32x4 __attribute__((ext_vector_type(4)));
typedef unsigned int u32;

#define MFMA __builtin_amdgcn_mfma_f32_16x16x32_f16
#define WGSCOPE __HIP_MEMORY_SCOPE_WORKGROUP

constexpr int Bsz = 256, T = 512, D = 128, H = 512, C = 128;
constexpr int ROWS = 16;          // batch rows per block (MFMA M)
constexpr int TPB  = 256;         // 4 waves, 1 wave/SIMD (512-VGPR budget)
constexpr int NW   = 4;           // waves
constexpr int NTW  = 8;           // n-tiles per wave (4*8 = 32 = NTG)
constexpr int LDH  = H + 8;       // b128 bank-uniform stride
constexpr int LDX  = D + 8;
constexpr int NTG  = H / 16;      // 32 n-tiles over H
constexpr int PKT  = 13;          // Whh k-tiles pinned in regs (kt 0..12, 416 VGPR)
constexpr int KTL  = 3;           // Whh k-tiles in LDS (kt 13..15, 96 KB)
constexpr size_t XSTRIDE = (size_t)16 * NTG * 256;  // xproj elems per timestep

// Pack fp32 [K][N] row-major -> fp16 MFMA-fragment order.
// k-slot map (BIJECTION, must match load_a): k = kt*32 + 8*(lane>>4) + e.
__global__ void pack_w(const float* __restrict__ W, int K, int N, f16* __restrict__ out) {
    int total = K * N;
    int NT = N / 16;
    for (int idx = blockIdx.x * blockDim.x + threadIdx.x; idx < total;
         idx += gridDim.x * blockDim.x) {
        int e    = idx & 7;
        int lane = (idx >> 3) & 63;
        int tile = idx >> 9;
        int kt = tile / NT, nt = tile % NT;
        int k = kt * 32 + 8 * (lane >> 4) + e;
        int n = nt * 16 + (lane & 15);
        out[idx] = (f16)W[(size_t)k * N + n];
    }
}

__device__ __forceinline__ f16x8 load_a(const f16* base, int ld, int kt, int l15, int l4) {
    return *(const f16x8*)(base + l15 * ld + kt * 32 + 8 * l4);
}

// tanh(v) = 1 - 2/(e^{2v}+1); exp->inf => rcp->0 => +/-1 (no clamp needed).
__device__ __forceinline__ float fast_tanh(float v) {
    float e = __expf(2.f * v);
    return 1.f - __fdividef(2.f, e + 1.f);
}

// xproj = x_t @ Whx + bh in MFMA C-fragment order (f16). Runs on all CUs once.
__global__ __launch_bounds__(512, 2) void xproj_k(
    const float* __restrict__ x, const f16* __restrict__ wpack,
    const float* __restrict__ bh, f16* __restrict__ xp) {
    const f16* Whx_p = wpack;
    __shared__ __align__(16) f16 xb[2][ROWS][LDX];
    const int tid = threadIdx.x, lane = tid & 63, w = tid >> 6;
    const int l15 = lane & 15, l4 = lane >> 4;
    const int bt = blockIdx.x;       // 0..15
    const int t0 = blockIdx.y * 16;  // chunks of 16 timesteps
    const int b0 = bt * ROWS;
    const int xrow = tid >> 5, xd0 = (tid & 31) * 4;
    const int ntg0 = w * 4;

    float bh4[4];
#pragma unroll
    for (int nt = 0; nt < 4; nt++) bh4[nt] = bh[(ntg0 + nt) * 16 + l15];
    {
        float4 v = *(const float4*)&x[((size_t)(b0 + xrow) * T + t0) * D + xd0];
        f16x4 h4 = {(f16)v.x, (f16)v.y, (f16)v.z, (f16)v.w};
        *(f16x4*)&xb[0][xrow][xd0] = h4;
    }
    __syncthreads();

    int p = 0;
    for (int tt = 0; tt < 16; tt++) {
        int t = t0 + tt;
        float4 xv;
        const bool havex = (tt + 1 < 16);
        if (havex)
            xv = *(const float4*)&x[((size_t)(b0 + xrow) * T + (t + 1)) * D + xd0];
        f32x4 acc[4];
#pragma unroll
        for (int nt = 0; nt < 4; nt++)
            acc[nt] = (f32x4){bh4[nt], bh4[nt], bh4[nt], bh4[nt]};
#pragma unroll
        for (int kt = 0; kt < D / 32; kt++) {
            f16x8 a = load_a(&xb[p][0][0], LDX, kt, l15, l4);
            const f16* btp = Whx_p + (((size_t)kt * NTG + ntg0) * 64 + lane) * 8;
#pragma unroll
            for (int nt = 0; nt < 4; nt++) {
                f16x8 b = *(const f16x8*)(btp + (size_t)nt * 512);
                acc[nt] = MFMA(a, b, acc[nt], 0, 0, 0);
            }
        }
        if (havex) {
            f16x4 h4 = {(f16)xv.x, (f16)xv.y, (f16)xv.z, (f16)xv.w};
            *(f16x4*)&xb[p ^ 1][xrow][xd0] = h4;
        }
        f16* op = xp + (((size_t)t * 16 + bt) * NTG + ntg0) * 256 + (size_t)lane * 4;
#pragma unroll
        for (int nt = 0; nt < 4; nt++) {
            f16x4 v = {(f16)acc[nt][0], (f16)acc[nt][1], (f16)acc[nt][2],
                       (f16)acc[nt][3]};
            *(f16x4*)(op + (size_t)nt * 256) = v;
        }
        __syncthreads();
        p ^= 1;
    }
}

// XP=2: f16 xproj + flag-synced loop. XP=0: in-loop Whx, barrier-synced.
// 4 waves, 1/SIMD: wave w owns h-cols [w*128,+128) (n-tiles w*8..w*8+7).
// ALL Whh resident: kt 0..12 in 416 VGPRs, kt 13..15 in LDS. Zero per-step
// weight streaming; LDS traffic/step = 64KB A + 96KB B + 16KB writes.
template <int XP>
__global__ __launch_bounds__(TPB, 1) void rnn_main(
    const float* __restrict__ x, const f16* __restrict__ wpack,
    const void* __restrict__ xproj, const float* __restrict__ bh,
    const float* __restrict__ bp, float* __restrict__ out) {
    const f16* Whx_p = wpack;
    const f16* Whh_p = wpack + D * H;
    const f16* Wph_p = wpack + D * H + H * H;

    __shared__ __align__(16) f16 hbuf[3][ROWS][LDH];           // 49.9 KB ring
    __shared__ __align__(16) f16 whh_lds[KTL * NTG * 64 * 8];  // 96 KB, kt 13..15
    __shared__ u32 pflag[NW];  // pflag[v]=s: wave v's h-cols of h_s readable
    __shared__ __align__(16) f16 xbuf[(XP == 0) ? 2 : 1][(XP == 0) ? ROWS : 1]
                                     [(XP == 0) ? LDX : 8];

    const int tid = threadIdx.x, lane = tid & 63, w = tid >> 6;  // w: 0..3
    const int l15 = lane & 15, l4 = lane >> 4;
    const int b0 = blockIdx.x * ROWS;
    const int xrow = tid >> 4, xc = (tid & 15) * 8;  // XP0 staging: 16x16 thr
    const int ntg0 = w * NTW;

    // Pinned Whh kt 0..12 for this wave's 8 n-tiles (416 VGPRs).
    f16x8 wreg[PKT][NTW];
#pragma unroll
    for (int kt = 0; kt < PKT; kt++)
#pragma unroll
        for (int nt = 0; nt < NTW; nt++)
            wreg[kt][nt] =
                *(const f16x8*)(Whh_p + (((size_t)kt * NTG + ntg0 + nt) * 64 + lane) * 8);

    // Stage Whh kt 13..15 into LDS.
    {
        const f16* src = Whh_p + (size_t)PKT * NTG * 512;
        for (int i = tid; i < KTL * NTG * 64; i += TPB)
            *(f16x8*)&whh_lds[(size_t)i * 8] = *(const f16x8*)(src + (size_t)i * 8);
    }
    for (int i = tid; i < ROWS * LDH; i += TPB) (&hbuf[0][0][0])[i] = (f16)0.f;
    if (tid < NW) pflag[tid] = 0u;  // h_0 ready

    float bh8[NTW];
    const f16* xph = nullptr;
    if constexpr (XP == 2) {
        xph = (const f16*)xproj + (((size_t)blockIdx.x * NTG + ntg0) * 64 + lane) * 4;
    } else {
#pragma unroll
        for (int nt = 0; nt < NTW; nt++) bh8[nt] = bh[(ntg0 + nt) * 16 + l15];
        const float* xr0 = &x[((size_t)(b0 + xrow) * T + 0) * D + xc];
        float4 v0 = *(const float4*)xr0;
        float4 v1 = *(const float4*)(xr0 + 4);
        f16x4 h0 = {(f16)v0.x, (f16)v0.y, (f16)v0.z, (f16)v0.w};
        f16x4 h1 = {(f16)v1.x, (f16)v1.y, (f16)v1.z, (f16)v1.w};
        *(f16x4*)&xbuf[0][xrow][xc] = h0;
        *(f16x4*)&xbuf[0][xrow][xc + 4] = h1;
    }
    __syncthreads();  // one-time: init visible
    __builtin_amdgcn_s_setprio(1);

    // Acquire-spin on producer v's publish (skip own). Early-exit; on miss
    // drop prio + s_sleep per retry.
    auto spin = [&](int v, u32 tgt) {
        if (v != w) {
            if (__hip_atomic_load(&pflag[v], __ATOMIC_ACQUIRE, WGSCOPE) >= tgt)
                return;
            __builtin_amdgcn_s_setprio(0);
            do {
                __builtin_amdgcn_s_sleep(1);
            } while (__hip_atomic_load(&pflag[v], __ATOMIC_ACQUIRE, WGSCOPE) < tgt);
            __builtin_amdgcn_s_setprio(1);
        }
    };

    // One timestep: reads h_t from hb, writes h_{t+1} to hw.
    auto body = [&](u32 t, const f16* hb, f16* hw, int pp) {
        u32 zo = 0;
        asm volatile("" : "+v"(zo));  // opaque: stop LICM hoisting LDS B reads
        const f16x8* wlds = (const f16x8*)whh_lds + zo;

        // issue this step's xproj fragment loads early (consumed pre-tanh)
        f16x4 xr16[NTW];
        if constexpr (XP == 2) {
            const f16* xq = xph + (size_t)t * XSTRIDE;
#pragma unroll
            for (int nt = 0; nt < NTW; nt++)
                xr16[nt] = *(const f16x4*)(xq + (size_t)nt * 256);
        }

        f32x4 acc[NTW];
        if constexpr (XP == 0) {
#pragma unroll
            for (int nt = 0; nt < NTW; nt++)
                acc[nt] = (f32x4){bh8[nt], bh8[nt], bh8[nt], bh8[nt]};
        } else {
#pragma unroll
            for (int nt = 0; nt < NTW; nt++) acc[nt] = (f32x4){0.f, 0.f, 0.f, 0.f};
        }

        if constexpr (XP == 0) {
            float4 xv0, xv1;
            const bool havex = (t + 1 < T);
            if (havex) {
                const float* xr = &x[((size_t)(b0 + xrow) * T + (t + 1)) * D + xc];
                xv0 = *(const float4*)xr;
                xv1 = *(const float4*)(xr + 4);
            }
            uintptr_t wxu = (uintptr_t)Whx_p;
            asm volatile("" : "+s"(wxu));
            const f16* wxs = (const f16*)wxu;
#pragma unroll
            for (int kt = 0; kt < D / 32; kt++) {
                f16x8 a = load_a(&xbuf[pp][0][0], LDX, kt, l15, l4);
                const f16* bt = wxs + (((size_t)kt * NTG + ntg0) * 64 + lane) * 8;
#pragma unroll
                for (int nt = 0; nt < NTW; nt++) {
                    f16x8 b = *(const f16x8*)(bt + (size_t)nt * 512);
                    acc[nt] = MFMA(a, b, acc[nt], 0, 0, 0);
                }
            }
            if (havex) {
                f16x4 h0 = {(f16)xv0.x, (f16)xv0.y, (f16)xv0.z, (f16)xv0.w};
                f16x4 h1 = {(f16)xv1.x, (f16)xv1.y, (f16)xv1.z, (f16)xv1.w};
                *(f16x4*)&xbuf[pp ^ 1][xrow][xc] = h0;
                *(f16x4*)&xbuf[pp ^ 1][xrow][xc + 4] = h1;
            }
        }

        // ---- h @ Whh: 16 positions; kt<13 reg-B, kt>=13 LDS-B ----
        // A-fragment kt needs h-cols [kt*32,+32) -> producer wave kt>>2;
        // spin before kt 0,4,8,12 = full producer coverage.
        auto pos = [&](auto ktc) {
            constexpr int kt = decltype(ktc)::value;
            if constexpr (XP != 0) {
                if constexpr ((kt & 3) == 0) spin(kt >> 2, t);
            }
            f16x8 a = load_a(hb, LDH, kt, l15, l4);
            if constexpr (kt < PKT) {
#pragma unroll
                for (int nt = 0; nt < NTW; nt++)
                    acc[nt] = MFMA(a, wreg[kt][nt], acc[nt], 0, 0, 0);
            } else {
#pragma unroll
                for (int nt = 0; nt < NTW; nt++)
                    acc[nt] = MFMA(
                        a, wlds[((size_t)(kt - PKT) * NTG + ntg0 + nt) * 64 + lane],
                        acc[nt], 0, 0, 0);
            }
        };
#define POS(J) pos(std::integral_constant<int, J>{})
        POS(0);  POS(1);  POS(2);  POS(3);
        POS(4);  POS(5);  POS(6);  POS(7);
        POS(8);  POS(9);  POS(10); POS(11);
        POS(12); POS(13); POS(14); POS(15);
#undef POS

        // h_new = tanh(acc [+ xproj]); C/D: col=lane&15, row=4*(lane>>4)+r
#pragma unroll
        for (int nt = 0; nt < NTW; nt++)
#pragma unroll
            for (int r = 0; r < 4; r++) {
                float v = acc[nt][r];
                if constexpr (XP == 2) v += (float)xr16[nt][r];
                float th = fast_tanh(v);
                hw[(l4 * 4 + r) * LDH + (ntg0 + nt) * 16 + l15] = (f16)th;
            }
        if constexpr (XP != 0) {
            if (lane == 0)
                __hip_atomic_store(&pflag[w], t + 1, __ATOMIC_RELEASE, WGSCOPE);
        } else {
            __syncthreads();
        }
    };

    f16* r0 = &hbuf[0][0][0];
    f16* r1 = &hbuf[1][0][0];
    f16* r2 = &hbuf[2][0][0];
#pragma unroll 1
    for (u32 t = 0; t < T; t++) {
        body(t, r0, r1, (int)(t & 1));
        f16* tmp = r0;
        r0 = r1;
        r1 = r2;
        r2 = tmp;  // h_{t+1} now in r0
    }
    // h_T in r0

    // wait for all waves' h_T, then out = h_T @ Wph + bp
    if constexpr (XP != 0) {
        __builtin_amdgcn_s_setprio(0);
        for (;;) {
            u32 f = __hip_atomic_load(&pflag[lane & 3], __ATOMIC_ACQUIRE, WGSCOPE);
            if (((u32)__ballot(f >= (u32)T) & 0xfu) == 0xfu) break;
            __builtin_amdgcn_s_sleep(1);
        }
        __builtin_amdgcn_s_setprio(1);
    } else {
        __syncthreads();
    }
    {
        // wave w owns output col-tiles {2w, 2w+1} (C/16 = 8 tiles)
#pragma unroll
        for (int e = 0; e < 2; e++) {
            const int ct = w * 2 + e;
            float bpv = bp[ct * 16 + l15];
            f32x4 acc = {bpv, bpv, bpv, bpv};
#pragma unroll 4
            for (int kt = 0; kt < H / 32; kt++) {
                f16x8 a = load_a(r0, LDH, kt, l15, l4);
                f16x8 b =
                    *(const f16x8*)(Wph_p + (((size_t)kt * (C / 16) + ct) * 64 + lane) * 8);
                acc = MFMA(a, b, acc, 0, 0, 0);
            }
#pragma unroll
            for (int r = 0; r < 4; r++)
                out[(size_t)(b0 + l4 * 4 + r) * C + ct * 16 + l15] = acc[r];
        }
    }
}

extern "C" void kernel_launch(void* const* d_in, const int* in_sizes, int n_in,
                              void* d_out, int out_size, void* d_ws, size_t ws_size,
                              hipStream_t stream) {
    const float* x   = (const float*)d_in[0];
    const float* Whx = (const float*)d_in[1];
    const float* Whh = (const float*)d_in[2];
    const float* Wph = (const float*)d_in[3];
    const float* bh  = (const float*)d_in[4];
    const float* bp  = (const float*)d_in[5];

    f16* wp = (f16*)d_ws; // 768 KB packed fp16 weights
    pack_w<<<dim3(128), 256, 0, stream>>>(Whx, D, H, wp);
    pack_w<<<dim3(512), 256, 0, stream>>>(Whh, H, H, wp + D * H);
    pack_w<<<dim3(128), 256, 0, stream>>>(Wph, H, C, wp + D * H + H * H);

    const size_t wbytes = (size_t)(D * H + H * H + H * C) * sizeof(f16); // 768 KB
    const size_t xpel   = (size_t)T * 16 * NTG * 256;                    // 67.1M elems

    if (ws_size >= wbytes + xpel * sizeof(f16)) {          // 129 MB: f16 xproj
        f16* xpb = (f16*)((char*)d_ws + wbytes);
        xproj_k<<<dim3(16, T / 16), 512, 0, stream>>>(x, wp, bh, xpb);
        rnn_main<2><<<dim3(Bsz / ROWS), TPB, 0, stream>>>(x, wp, xpb, bh, bp,
                                                          (float*)d_out);
    } else {                                               // fallback: in-loop Whx
        rnn_main<0><<<dim3(Bsz / ROWS), TPB, 0, stream>>>(x, wp, nullptr, bh, bp,
                                                          (float*)d_out);
    }
}

// Round 10
// 1401.356 us; speedup vs baseline: 1.4056x; 1.4056x over previous
//
#include <hip/hip_runtime.h>
#include <type_traits>

typedef _Float16 f16;
typedef f16 f16x4 __attribute__((ext_vector_type(4)));
typedef f16 f16x8 __attribute__((ext_vector_type(8)));
typedef float f32x4 __attribute__((ext_vector_type(4)));
typedef unsigned int u32;

#define MFMA __builtin_amdgcn_mfma_f32_16x16x32_f16
#define WGSCOPE __HIP_MEMORY_SCOPE_WORKGROUP

constexpr int Bsz = 256, T = 512, D = 128, H = 512, C = 128;
constexpr int ROWS = 16;          // batch rows per block (MFMA M)
constexpr int TPB  = 512;         // 8 waves, 2/SIMD
constexpr int LDH  = H + 8;       // b128 bank-uniform stride
constexpr int LDX  = D + 8;
constexpr int NTG  = H / 16;      // 32 n-tiles over H
constexpr int PKT  = 8;           // Whh k-tiles pinned in regs (kt 0..7)
constexpr int KTL  = 3;           // Whh k-tiles in LDS (kt 8..10); kt 11..15 streamed
constexpr size_t XSTRIDE = (size_t)16 * NTG * 256;  // xproj elems per timestep

// Pack fp32 [K][N] row-major -> fp16 MFMA-fragment order.
// k-slot map (BIJECTION, must match load_a): k = kt*32 + 8*(lane>>4) + e.
__global__ void pack_w(const float* __restrict__ W, int K, int N, f16* __restrict__ out) {
    int total = K * N;
    int NT = N / 16;
    for (int idx = blockIdx.x * blockDim.x + threadIdx.x; idx < total;
         idx += gridDim.x * blockDim.x) {
        int e    = idx & 7;
        int lane = (idx >> 3) & 63;
        int tile = idx >> 9;
        int kt = tile / NT, nt = tile % NT;
        int k = kt * 32 + 8 * (lane >> 4) + e;
        int n = nt * 16 + (lane & 15);
        out[idx] = (f16)W[(size_t)k * N + n];
    }
}

__device__ __forceinline__ f16x8 load_a(const f16* base, int ld, int kt, int l15, int l4) {
    return *(const f16x8*)(base + l15 * ld + kt * 32 + 8 * l4);
}

// tanh(v) = 1 - 2/(2^(v*2*log2e)+1); exp2 direct, constant folded.
// Overflow-safe: exp2->inf => rcp->0 => +/-1.
__device__ __forceinline__ float fast_tanh(float v) {
    float e = __builtin_amdgcn_exp2f(v * 2.885390081777927f);  // 2*log2(e)
    return 1.f - __fdividef(2.f, e + 1.f);
}

// xproj = x_t @ Whx + bh in MFMA C-fragment order (f32 or f16). Runs on all CUs.
template <typename OT>
__global__ __launch_bounds__(TPB, 2) void xproj_k(
    const float* __restrict__ x, const f16* __restrict__ wpack,
    const float* __restrict__ bh, OT* __restrict__ xp) {
    const f16* Whx_p = wpack;
    __shared__ __align__(16) f16 xb[2][ROWS][LDX];
    const int tid = threadIdx.x, lane = tid & 63, w = tid >> 6;
    const int l15 = lane & 15, l4 = lane >> 4;
    const int bt = blockIdx.x;       // 0..15
    const int t0 = blockIdx.y * 16;  // chunks of 16 timesteps
    const int b0 = bt * ROWS;
    const int xrow = tid >> 5, xd0 = (tid & 31) * 4;
    const int ntg0 = w * 4;

    float bh4[4];
#pragma unroll
    for (int nt = 0; nt < 4; nt++) bh4[nt] = bh[(ntg0 + nt) * 16 + l15];
    {
        float4 v = *(const float4*)&x[((size_t)(b0 + xrow) * T + t0) * D + xd0];
        f16x4 h4 = {(f16)v.x, (f16)v.y, (f16)v.z, (f16)v.w};
        *(f16x4*)&xb[0][xrow][xd0] = h4;
    }
    __syncthreads();

    int p = 0;
    for (int tt = 0; tt < 16; tt++) {
        int t = t0 + tt;
        float4 xv;
        const bool havex = (tt + 1 < 16);
        if (havex)
            xv = *(const float4*)&x[((size_t)(b0 + xrow) * T + (t + 1)) * D + xd0];
        f32x4 acc[4];
#pragma unroll
        for (int nt = 0; nt < 4; nt++)
            acc[nt] = (f32x4){bh4[nt], bh4[nt], bh4[nt], bh4[nt]};
#pragma unroll
        for (int kt = 0; kt < D / 32; kt++) {
            f16x8 a = load_a(&xb[p][0][0], LDX, kt, l15, l4);
            const f16* btp = Whx_p + (((size_t)kt * NTG + ntg0) * 64 + lane) * 8;
#pragma unroll
            for (int nt = 0; nt < 4; nt++) {
                f16x8 b = *(const f16x8*)(btp + (size_t)nt * 512);
                acc[nt] = MFMA(a, b, acc[nt], 0, 0, 0);
            }
        }
        if (havex) {
            f16x4 h4 = {(f16)xv.x, (f16)xv.y, (f16)xv.z, (f16)xv.w};
            *(f16x4*)&xb[p ^ 1][xrow][xd0] = h4;
        }
        OT* op = xp + (((size_t)t * 16 + bt) * NTG + ntg0) * 256 + (size_t)lane * 4;
#pragma unroll
        for (int nt = 0; nt < 4; nt++) {
            if constexpr (std::is_same_v<OT, float>) {
                *(f32x4*)(op + (size_t)nt * 256) = acc[nt];
            } else {
                f16x4 v = {(f16)acc[nt][0], (f16)acc[nt][1], (f16)acc[nt][2],
                           (f16)acc[nt][3]};
                *(f16x4*)(op + (size_t)nt * 256) = v;
            }
        }
        __syncthreads();
        p ^= 1;
    }
}

// XP=1: f32 xproj. XP=2: f16 xproj. XP=0: in-loop Whx fallback (barrier-synced).
// XP!=0: no per-step barrier — producer/consumer LDS flags + 3-ring hbuf.
template <int XP>
__global__ __launch_bounds__(TPB, 2) void rnn_main(
    const float* __restrict__ x, const f16* __restrict__ wpack,
    const void* __restrict__ xproj, const float* __restrict__ bh,
    const float* __restrict__ bp, float* __restrict__ out) {
    const f16* Whx_p = wpack;
    const f16* Whh_p = wpack + D * H;
    const f16* Wph_p = wpack + D * H + H * H;

    __shared__ __align__(16) f16 hbuf[3][ROWS][LDH];           // 49.9 KB ring
    __shared__ __align__(16) f16 whh_lds[KTL * NTG * 64 * 8];  // 96 KB, kt 8..10
    __shared__ u32 pflag[8];  // pflag[v]=s: wave v's chunk of h_s readable
    __shared__ __align__(16) f16 xbuf[(XP == 0) ? 2 : 1][(XP == 0) ? ROWS : 1]
                                     [(XP == 0) ? LDX : 8];

    const int tid = threadIdx.x, lane = tid & 63, w = tid >> 6;
    const int l15 = lane & 15, l4 = lane >> 4;
    const int b0 = blockIdx.x * ROWS;
    const int xrow = tid >> 5, xd0 = (tid & 31) * 4;
    const int ntg0 = w * 4;

    // Pinned Whh kt 0..7 (128 regs, AGPR-resident; 2-wave/SIMD budget is full:
    // R9 showed PKT beyond this spills — do not raise).
    f16x8 wreg[PKT][4];
#pragma unroll
    for (int kt = 0; kt < PKT; kt++)
#pragma unroll
        for (int nt = 0; nt < 4; nt++)
            wreg[kt][nt] =
                *(const f16x8*)(Whh_p + (((size_t)kt * NTG + ntg0 + nt) * 64 + lane) * 8);

    // Stage Whh kt 8..10 into LDS.
    {
        const f16* src = Whh_p + (size_t)PKT * NTG * 512;
        for (int i = tid; i < KTL * NTG * 64; i += TPB)
            *(f16x8*)&whh_lds[(size_t)i * 8] = *(const f16x8*)(src + (size_t)i * 8);
    }
    for (int i = tid; i < ROWS * LDH; i += TPB) (&hbuf[0][0][0])[i] = (f16)0.f;
    if (tid < 8) pflag[tid] = 0u;  // h_0 ready

    float bh4[4];
    const float* xpf = nullptr;
    const f16* xph = nullptr;
    if constexpr (XP == 1) {
        xpf = (const float*)xproj + (((size_t)blockIdx.x * NTG + ntg0) * 64 + lane) * 4;
    } else if constexpr (XP == 2) {
        xph = (const f16*)xproj + (((size_t)blockIdx.x * NTG + ntg0) * 64 + lane) * 4;
    } else {
#pragma unroll
        for (int nt = 0; nt < 4; nt++) bh4[nt] = bh[(ntg0 + nt) * 16 + l15];
        float4 v = *(const float4*)&x[((size_t)(b0 + xrow) * T + 0) * D + xd0];
        f16x4 h4 = {(f16)v.x, (f16)v.y, (f16)v.z, (f16)v.w};
        *(f16x4*)&xbuf[0][xrow][xd0] = h4;
    }

    // Prologue: preload streamed kt 11 -> sA, kt 12 -> sB.
    f16x8 sA[4], sB[4];
    {
        const f16* wb0 = Whh_p + ((size_t)ntg0 * 64 + lane) * 8;
#pragma unroll
        for (int nt = 0; nt < 4; nt++)
            sA[nt] = *(const f16x8*)(wb0 + ((size_t)11 * NTG + nt) * 512);
#pragma unroll
        for (int nt = 0; nt < 4; nt++)
            sB[nt] = *(const f16x8*)(wb0 + ((size_t)12 * NTG + nt) * 512);
    }
    __syncthreads();  // one-time: init + pflag visible
    __builtin_amdgcn_s_setprio(1);

    // Acquire-spin on producer v (no-op for own tiles). Early-exit; on miss
    // drop prio + s_sleep per retry (issue-slot hygiene).
    auto spin = [&](int v, u32 tgt) {
        if constexpr (XP != 0) {
            if (v != w) {
                if (__hip_atomic_load(&pflag[v], __ATOMIC_ACQUIRE, WGSCOPE) >= tgt)
                    return;
                __builtin_amdgcn_s_setprio(0);
                do {
                    __builtin_amdgcn_s_sleep(1);
                } while (__hip_atomic_load(&pflag[v], __ATOMIC_ACQUIRE, WGSCOPE) < tgt);
                __builtin_amdgcn_s_setprio(1);
            }
        }
    };

    // One timestep: reads h_t from hb, writes h_{t+1} to hw.
    // Entry: bA=kt11, bB=kt12 prefetched. Exit: bA=kt12', bB=kt11' (roles swap).
    auto body = [&](u32 t, const f16* hb, f16* hw, f16x8(&bA)[4], f16x8(&bB)[4],
                    int pp) {
        uintptr_t whu = (uintptr_t)Whh_p;
        asm volatile("" : "+s"(whu));  // defeat LICM on invariant weight loads
        const f16* wbase = (const f16*)whu + ((size_t)ntg0 * 64 + lane) * 8;
        u32 zo = 0;
        asm volatile("" : "+v"(zo));
        const f16x8* wlds = (const f16x8*)whh_lds + zo;

        // issue this step's xproj fragment loads (consumed pre-tanh)
        f32x4 xr32[4];
        f16x4 xr16[4];
        if constexpr (XP == 1) {
            const float* xq = xpf + (size_t)t * XSTRIDE;
#pragma unroll
            for (int nt = 0; nt < 4; nt++) xr32[nt] = *(const f32x4*)(xq + (size_t)nt * 256);
        } else if constexpr (XP == 2) {
            const f16* xq = xph + (size_t)t * XSTRIDE;
#pragma unroll
            for (int nt = 0; nt < 4; nt++) xr16[nt] = *(const f16x4*)(xq + (size_t)nt * 256);
        }

        f32x4 acc[4];
        if constexpr (XP == 0) {
#pragma unroll
            for (int nt = 0; nt < 4; nt++)
                acc[nt] = (f32x4){bh4[nt], bh4[nt], bh4[nt], bh4[nt]};
        } else {
#pragma unroll
            for (int nt = 0; nt < 4; nt++) acc[nt] = (f32x4){0.f, 0.f, 0.f, 0.f};
        }

        if constexpr (XP == 0) {
            float4 xv;
            const bool havex = (t + 1 < T);
            if (havex)
                xv = *(const float4*)&x[((size_t)(b0 + xrow) * T + (t + 1)) * D + xd0];
            uintptr_t wxu = (uintptr_t)Whx_p;
            asm volatile("" : "+s"(wxu));
            const f16* wxs = (const f16*)wxu;
#pragma unroll
            for (int kt = 0; kt < D / 32; kt++) {
                f16x8 a = load_a(&xbuf[pp][0][0], LDX, kt, l15, l4);
                const f16* bt = wxs + (((size_t)kt * NTG + ntg0) * 64 + lane) * 8;
#pragma unroll
                for (int nt = 0; nt < 4; nt++) {
                    f16x8 b = *(const f16x8*)(bt + (size_t)nt * 512);
                    acc[nt] = MFMA(a, b, acc[nt], 0, 0, 0);
                }
            }
            if (havex) {
                f16x4 h4 = {(f16)xv.x, (f16)xv.y, (f16)xv.z, (f16)xv.w};
                *(f16x4*)&xbuf[pp ^ 1][xrow][xd0] = h4;
            }
        }

        // ---- h @ Whh: pinned kt0..7 | LDS kt8..10 | streamed kt11..15 ----
        // Producer of A-fragment kt is wave kt>>1.
        auto LS = [&](int kt, f16x8(&bf)[4]) {
#pragma unroll
            for (int nt = 0; nt < 4; nt++)
                bf[nt] = *(const f16x8*)(wbase + ((size_t)kt * NTG + nt) * 512);
        };
        auto PK = [&](int kt) {
            f16x8 a = load_a(hb, LDH, kt, l15, l4);
#pragma unroll
            for (int nt = 0; nt < 4; nt++)
                acc[nt] = MFMA(a, wreg[kt][nt], acc[nt], 0, 0, 0);
        };
        auto CL = [&](int ktl) {
            f16x8 a = load_a(hb, LDH, PKT + ktl, l15, l4);
#pragma unroll
            for (int nt = 0; nt < 4; nt++)
                acc[nt] = MFMA(a, wlds[((size_t)ktl * NTG + ntg0 + nt) * 64 + lane],
                               acc[nt], 0, 0, 0);
        };
        auto CS = [&](int kt, f16x8(&bf)[4]) {
            f16x8 a = load_a(hb, LDH, kt, l15, l4);
#pragma unroll
            for (int nt = 0; nt < 4; nt++) acc[nt] = MFMA(a, bf[nt], acc[nt], 0, 0, 0);
        };

        // Schedule: all streams at >=6-position load-use distance; CLs
        // interleaved where streams would stall; spin before FIRST use of
        // each producer (full 8-producer coverage).
        /*pos0 */ spin(0, t); PK(0);
        /*pos1 */             PK(1);
        /*pos2 */ spin(5, t); CS(11, bA); LS(13, bA);
        /*pos3 */ spin(1, t); PK(2);
        /*pos4 */             PK(3);
        /*pos5 */ spin(6, t); CS(12, bB); LS(14, bB);
        /*pos6 */ spin(4, t); CL(0);
        /*pos7 */ spin(2, t); PK(4);
        /*pos8 */             CS(13, bA); LS(15, bA);
        /*pos9 */             PK(5);
        /*pos10*/             CL(1);
        /*pos11*/ spin(7, t); CS(14, bB); LS(11, bB);   // next-step kt11
        /*pos12*/ spin(3, t); PK(6);
        /*pos13*/             CL(2);
        /*pos14*/             CS(15, bA); LS(12, bA);   // next-step kt12
        /*pos15*/             PK(7);

        // h_new = tanh(acc [+ xproj]); C/D layout: col=lane&15, row=4*(lane>>4)+r
#pragma unroll
        for (int nt = 0; nt < 4; nt++)
#pragma unroll
            for (int r = 0; r < 4; r++) {
                float v = acc[nt][r];
                if constexpr (XP == 1) v += xr32[nt][r];
                else if constexpr (XP == 2) v += (float)xr16[nt][r];
                float th = fast_tanh(v);
                hw[(l4 * 4 + r) * LDH + (ntg0 + nt) * 16 + l15] = (f16)th;
            }
        if constexpr (XP != 0) {
            if (lane == 0)
                __hip_atomic_store(&pflag[w], t + 1, __ATOMIC_RELEASE, WGSCOPE);
        } else {
            __syncthreads();
        }
    };

    f16* r0 = &hbuf[0][0][0];
    f16* r1 = &hbuf[1][0][0];
    f16* r2 = &hbuf[2][0][0];
    for (u32 t = 0; t < T; t += 2) {
        body(t,     r0, r1, sA, sB, 0);  // exit: sB=kt11', sA=kt12'
        body(t + 1, r1, r2, sB, sA, 1);  // exit: sA=kt11'', sB=kt12''
        f16* n0 = r2; f16* n1 = r0; f16* n2 = r1;  // 3-ring rotate by 2
        r0 = n0; r1 = n1; r2 = n2;
    }
    // after loop h_T sits in r0 (T even)

    // wait for all waves' h_T, then out = h_T @ Wph + bp
    if constexpr (XP != 0) {
        __builtin_amdgcn_s_setprio(0);
        for (;;) {
            u32 f = __hip_atomic_load(&pflag[lane & 7], __ATOMIC_ACQUIRE, WGSCOPE);
            if (((u32)__ballot(f >= (u32)T) & 0xffu) == 0xffu) break;
            __builtin_amdgcn_s_sleep(1);
        }
        __builtin_amdgcn_s_setprio(1);
    } else {
        __syncthreads();
    }
    {
        float bpv = bp[w * 16 + l15];
        f32x4 acc = {bpv, bpv, bpv, bpv};
#pragma unroll 4
        for (int kt = 0; kt < H / 32; kt++) {
            f16x8 a = load_a(r0, LDH, kt, l15, l4);
            f16x8 b = *(const f16x8*)(Wph_p + (((size_t)kt * (C / 16) + w) * 64 + lane) * 8);
            acc = MFMA(a, b, acc, 0, 0, 0);
        }
#pragma unroll
        for (int r = 0; r < 4; r++)
            out[(size_t)(b0 + l4 * 4 + r) * C + w * 16 + l15] = acc[r];
    }
}

extern "C" void kernel_launch(void* const* d_in, const int* in_sizes, int n_in,
                              void* d_out, int out_size, void* d_ws, size_t ws_size,
                              hipStream_t stream) {
    const float* x   = (const float*)d_in[0];
    const float* Whx = (const float*)d_in[1];
    const float* Whh = (const float*)d_in[2];
    const float* Wph = (const float*)d_in[3];
    const float* bh  = (const float*)d_in[4];
    const float* bp  = (const float*)d_in[5];

    f16* wp = (f16*)d_ws; // 768 KB packed fp16 weights
    pack_w<<<dim3(128), 256, 0, stream>>>(Whx, D, H, wp);
    pack_w<<<dim3(512), 256, 0, stream>>>(Whh, H, H, wp + D * H);
    pack_w<<<dim3(128), 256, 0, stream>>>(Wph, H, C, wp + D * H + H * H);

    const size_t wbytes = (size_t)(D * H + H * H + H * C) * sizeof(f16); // 768 KB
    const size_t xpel   = (size_t)T * 16 * NTG * 256;                    // 67.1M elems

    if (ws_size >= wbytes + xpel * sizeof(float)) {        // 257 MB: f32 xproj
        float* xpb = (float*)((char*)d_ws + wbytes);
        xproj_k<float><<<dim3(16, T / 16), TPB, 0, stream>>>(x, wp, bh, xpb);
        rnn_main<1><<<dim3(Bsz / ROWS), TPB, 0, stream>>>(x, wp, xpb, bh, bp,
                                                          (float*)d_out);
    } else if (ws_size >= wbytes + xpel * sizeof(f16)) {   // 129 MB: f16 xproj
        f16* xpb = (f16*)((char*)d_ws + wbytes);
        xproj_k<f16><<<dim3(16, T / 16), TPB, 0, stream>>>(x, wp, bh, xpb);
        rnn_main<2><<<dim3(Bsz / ROWS), TPB, 0, stream>>>(x, wp, xpb, bh, bp,
                                                          (float*)d_out);
    } else {                                               // fallback: in-loop Whx
        rnn_main<0><<<dim3(Bsz / ROWS), TPB, 0, stream>>>(x, wp, nullptr, bh, bp,
                                                          (float*)d_out);
    }
}

// Round 11
// 1322.142 us; speedup vs baseline: 1.4898x; 1.0599x over previous
//
#include <hip/hip_runtime.h>
#include <type_traits>

typedef _Float16 f16;
typedef f16 f16x4 __attribute__((ext_vector_type(4)));
typedef f16 f16x8 __attribute__((ext_vector_type(8)));
typedef float f32x4 __attribute__((ext_vector_type(4)));
typedef unsigned int u32;

#define MFMA __builtin_amdgcn_mfma_f32_16x16x32_f16
#define WGSCOPE __HIP_MEMORY_SCOPE_WORKGROUP

constexpr int Bsz = 256, T = 512, D = 128, H = 512, C = 128;
constexpr int ROWS = 16;          // batch rows per block (MFMA M)
constexpr int TPB  = 512;         // 8 waves, 2/SIMD
constexpr int LDH  = H + 8;       // b128 bank-uniform stride
constexpr int LDX  = D + 8;
constexpr int NTG  = H / 16;      // 32 n-tiles over H
constexpr int PKT  = 8;           // Whh k-tiles pinned in regs (kt 0..7)
constexpr int KTL  = 3;           // Whh k-tiles in LDS (kt 8..10); kt 11..15 streamed
constexpr size_t XSTRIDE = (size_t)16 * NTG * 256;  // xproj elems per timestep

// Pack fp32 [K][N] row-major -> fp16 MFMA-fragment order.
// k-slot map (BIJECTION, must match load_a): k = kt*32 + 8*(lane>>4) + e.
// perm=1 (Whx/Whh): column permutation within each 64-col wave group so tile
// nt owns cols {g*64 + (nt&3) + 4m} -> C-fragment values for fixed r are
// CONTIGUOUS across nt => h-write becomes one ds_write_b64 per r (was 16
// scalar b16 writes). h stays in true-column order; A-reads unchanged.
// perm=0 (Wph): plain n = nt*16 + m.
__global__ void pack_w(const float* __restrict__ W, int K, int N, int perm,
                       f16* __restrict__ out) {
    int total = K * N;
    int NT = N / 16;
    for (int idx = blockIdx.x * blockDim.x + threadIdx.x; idx < total;
         idx += gridDim.x * blockDim.x) {
        int e    = idx & 7;
        int lane = (idx >> 3) & 63;
        int tile = idx >> 9;
        int kt = tile / NT, nt = tile % NT;
        int k = kt * 32 + 8 * (lane >> 4) + e;
        int m = lane & 15;
        int n = perm ? ((nt >> 2) * 64 + (nt & 3) + 4 * m) : (nt * 16 + m);
        out[idx] = (f16)W[(size_t)k * N + n];
    }
}

__device__ __forceinline__ f16x8 load_a(const f16* base, int ld, int kt, int l15, int l4) {
    return *(const f16x8*)(base + l15 * ld + kt * 32 + 8 * l4);
}

// tanh(v) = 1 - 2/(2^(v*2*log2e)+1); exp2 direct, constant folded.
// Overflow-safe: exp2->inf => rcp->0 => +/-1.
__device__ __forceinline__ float fast_tanh(float v) {
    float e = __builtin_amdgcn_exp2f(v * 2.885390081777927f);  // 2*log2(e)
    return 1.f - __fdividef(2.f, e + 1.f);
}

// xproj = x_t @ Whx + bh in MFMA C-fragment order (f32 or f16). Runs on all CUs.
template <typename OT>
__global__ __launch_bounds__(TPB, 2) void xproj_k(
    const float* __restrict__ x, const f16* __restrict__ wpack,
    const float* __restrict__ bh, OT* __restrict__ xp) {
    const f16* Whx_p = wpack;
    __shared__ __align__(16) f16 xb[2][ROWS][LDX];
    const int tid = threadIdx.x, lane = tid & 63, w = tid >> 6;
    const int l15 = lane & 15, l4 = lane >> 4;
    const int bt = blockIdx.x;       // 0..15
    const int t0 = blockIdx.y * 16;  // chunks of 16 timesteps
    const int b0 = bt * ROWS;
    const int xrow = tid >> 5, xd0 = (tid & 31) * 4;
    const int ntg0 = w * 4;

    // permuted column meaning: tile ntg0+nt, slot l15 -> true col w*64+nt+4*l15
    float bh4[4];
#pragma unroll
    for (int nt = 0; nt < 4; nt++) bh4[nt] = bh[w * 64 + nt + 4 * l15];
    {
        float4 v = *(const float4*)&x[((size_t)(b0 + xrow) * T + t0) * D + xd0];
        f16x4 h4 = {(f16)v.x, (f16)v.y, (f16)v.z, (f16)v.w};
        *(f16x4*)&xb[0][xrow][xd0] = h4;
    }
    __syncthreads();

    int p = 0;
    for (int tt = 0; tt < 16; tt++) {
        int t = t0 + tt;
        float4 xv;
        const bool havex = (tt + 1 < 16);
        if (havex)
            xv = *(const float4*)&x[((size_t)(b0 + xrow) * T + (t + 1)) * D + xd0];
        f32x4 acc[4];
#pragma unroll
        for (int nt = 0; nt < 4; nt++)
            acc[nt] = (f32x4){bh4[nt], bh4[nt], bh4[nt], bh4[nt]};
#pragma unroll
        for (int kt = 0; kt < D / 32; kt++) {
            f16x8 a = load_a(&xb[p][0][0], LDX, kt, l15, l4);
            const f16* btp = Whx_p + (((size_t)kt * NTG + ntg0) * 64 + lane) * 8;
#pragma unroll
            for (int nt = 0; nt < 4; nt++) {
                f16x8 b = *(const f16x8*)(btp + (size_t)nt * 512);
                acc[nt] = MFMA(a, b, acc[nt], 0, 0, 0);
            }
        }
        if (havex) {
            f16x4 h4 = {(f16)xv.x, (f16)xv.y, (f16)xv.z, (f16)xv.w};
            *(f16x4*)&xb[p ^ 1][xrow][xd0] = h4;
        }
        OT* op = xp + (((size_t)t * 16 + bt) * NTG + ntg0) * 256 + (size_t)lane * 4;
#pragma unroll
        for (int nt = 0; nt < 4; nt++) {
            if constexpr (std::is_same_v<OT, float>) {
                *(f32x4*)(op + (size_t)nt * 256) = acc[nt];
            } else {
                f16x4 v = {(f16)acc[nt][0], (f16)acc[nt][1], (f16)acc[nt][2],
                           (f16)acc[nt][3]};
                *(f16x4*)(op + (size_t)nt * 256) = v;
            }
        }
        __syncthreads();
        p ^= 1;
    }
}

// XP=1: f32 xproj. XP=2: f16 xproj. XP=0: in-loop Whx fallback (barrier-synced).
// XP!=0: no per-step barrier — producer/consumer LDS flags + 3-ring hbuf.
template <int XP>
__global__ __launch_bounds__(TPB, 2) void rnn_main(
    const float* __restrict__ x, const f16* __restrict__ wpack,
    const void* __restrict__ xproj, const float* __restrict__ bh,
    const float* __restrict__ bp, float* __restrict__ out) {
    const f16* Whx_p = wpack;
    const f16* Whh_p = wpack + D * H;
    const f16* Wph_p = wpack + D * H + H * H;

    __shared__ __align__(16) f16 hbuf[3][ROWS][LDH];           // 49.9 KB ring
    __shared__ __align__(16) f16 whh_lds[KTL * NTG * 64 * 8];  // 96 KB, kt 8..10
    __shared__ u32 pflag[8];  // pflag[v]=s: wave v's chunk of h_s readable
    __shared__ __align__(16) f16 xbuf[(XP == 0) ? 2 : 1][(XP == 0) ? ROWS : 1]
                                     [(XP == 0) ? LDX : 8];

    const int tid = threadIdx.x, lane = tid & 63, w = tid >> 6;
    const int l15 = lane & 15, l4 = lane >> 4;
    const int b0 = blockIdx.x * ROWS;
    const int xrow = tid >> 5, xd0 = (tid & 31) * 4;
    const int ntg0 = w * 4;

    // Pinned Whh kt 0..7 (128 regs, AGPR-resident; 2-wave/SIMD budget is full:
    // R9 showed PKT beyond this spills — do not raise).
    f16x8 wreg[PKT][4];
#pragma unroll
    for (int kt = 0; kt < PKT; kt++)
#pragma unroll
        for (int nt = 0; nt < 4; nt++)
            wreg[kt][nt] =
                *(const f16x8*)(Whh_p + (((size_t)kt * NTG + ntg0 + nt) * 64 + lane) * 8);

    // Stage Whh kt 8..10 into LDS.
    {
        const f16* src = Whh_p + (size_t)PKT * NTG * 512;
        for (int i = tid; i < KTL * NTG * 64; i += TPB)
            *(f16x8*)&whh_lds[(size_t)i * 8] = *(const f16x8*)(src + (size_t)i * 8);
    }
    for (int i = tid; i < ROWS * LDH; i += TPB) (&hbuf[0][0][0])[i] = (f16)0.f;
    if (tid < 8) pflag[tid] = 0u;  // h_0 ready

    float bh4[4];
    const float* xpf = nullptr;
    const f16* xph = nullptr;
    if constexpr (XP == 1) {
        xpf = (const float*)xproj + (((size_t)blockIdx.x * NTG + ntg0) * 64 + lane) * 4;
    } else if constexpr (XP == 2) {
        xph = (const f16*)xproj + (((size_t)blockIdx.x * NTG + ntg0) * 64 + lane) * 4;
    } else {
#pragma unroll
        for (int nt = 0; nt < 4; nt++) bh4[nt] = bh[w * 64 + nt + 4 * l15];
        float4 v = *(const float4*)&x[((size_t)(b0 + xrow) * T + 0) * D + xd0];
        f16x4 h4 = {(f16)v.x, (f16)v.y, (f16)v.z, (f16)v.w};
        *(f16x4*)&xbuf[0][xrow][xd0] = h4;
    }

    // Prologue: preload streamed kt 11 -> sA, kt 12 -> sB.
    f16x8 sA[4], sB[4];
    {
        const f16* wb0 = Whh_p + ((size_t)ntg0 * 64 + lane) * 8;
#pragma unroll
        for (int nt = 0; nt < 4; nt++)
            sA[nt] = *(const f16x8*)(wb0 + ((size_t)11 * NTG + nt) * 512);
#pragma unroll
        for (int nt = 0; nt < 4; nt++)
            sB[nt] = *(const f16x8*)(wb0 + ((size_t)12 * NTG + nt) * 512);
    }
    __syncthreads();  // one-time: init + pflag visible
    __builtin_amdgcn_s_setprio(1);

    // Acquire-spin on producer v (no-op for own tiles). Early-exit; on miss
    // drop prio + s_sleep per retry (issue-slot hygiene).
    auto spin = [&](int v, u32 tgt) {
        if constexpr (XP != 0) {
            if (v != w) {
                if (__hip_atomic_load(&pflag[v], __ATOMIC_ACQUIRE, WGSCOPE) >= tgt)
                    return;
                __builtin_amdgcn_s_setprio(0);
                do {
                    __builtin_amdgcn_s_sleep(1);
                } while (__hip_atomic_load(&pflag[v], __ATOMIC_ACQUIRE, WGSCOPE) < tgt);
                __builtin_amdgcn_s_setprio(1);
            }
        }
    };

    // One timestep: reads h_t from hb, writes h_{t+1} to hw.
    // Entry: bA=kt11, bB=kt12 prefetched. Exit: bA=kt12', bB=kt11' (roles swap).
    auto body = [&](u32 t, const f16* hb, f16* hw, f16x8(&bA)[4], f16x8(&bB)[4],
                    int pp) {
        uintptr_t whu = (uintptr_t)Whh_p;
        asm volatile("" : "+s"(whu));  // defeat LICM on invariant weight loads
        const f16* wbase = (const f16*)whu + ((size_t)ntg0 * 64 + lane) * 8;
        u32 zo = 0;
        asm volatile("" : "+v"(zo));
        const f16x8* wlds = (const f16x8*)whh_lds + zo;

        // issue this step's xproj fragment loads (consumed pre-tanh)
        f32x4 xr32[4];
        f16x4 xr16[4];
        if constexpr (XP == 1) {
            const float* xq = xpf + (size_t)t * XSTRIDE;
#pragma unroll
            for (int nt = 0; nt < 4; nt++) xr32[nt] = *(const f32x4*)(xq + (size_t)nt * 256);
        } else if constexpr (XP == 2) {
            const f16* xq = xph + (size_t)t * XSTRIDE;
#pragma unroll
            for (int nt = 0; nt < 4; nt++) xr16[nt] = *(const f16x4*)(xq + (size_t)nt * 256);
        }

        f32x4 acc[4];
        if constexpr (XP == 0) {
#pragma unroll
            for (int nt = 0; nt < 4; nt++)
                acc[nt] = (f32x4){bh4[nt], bh4[nt], bh4[nt], bh4[nt]};
        } else {
#pragma unroll
            for (int nt = 0; nt < 4; nt++) acc[nt] = (f32x4){0.f, 0.f, 0.f, 0.f};
        }

        if constexpr (XP == 0) {
            float4 xv;
            const bool havex = (t + 1 < T);
            if (havex)
                xv = *(const float4*)&x[((size_t)(b0 + xrow) * T + (t + 1)) * D + xd0];
            uintptr_t wxu = (uintptr_t)Whx_p;
            asm volatile("" : "+s"(wxu));
            const f16* wxs = (const f16*)wxu;
#pragma unroll
            for (int kt = 0; kt < D / 32; kt++) {
                f16x8 a = load_a(&xbuf[pp][0][0], LDX, kt, l15, l4);
                const f16* bt = wxs + (((size_t)kt * NTG + ntg0) * 64 + lane) * 8;
#pragma unroll
                for (int nt = 0; nt < 4; nt++) {
                    f16x8 b = *(const f16x8*)(bt + (size_t)nt * 512);
                    acc[nt] = MFMA(a, b, acc[nt], 0, 0, 0);
                }
            }
            if (havex) {
                f16x4 h4 = {(f16)xv.x, (f16)xv.y, (f16)xv.z, (f16)xv.w};
                *(f16x4*)&xbuf[pp ^ 1][xrow][xd0] = h4;
            }
        }

        // ---- h @ Whh: pinned kt0..7 | LDS kt8..10 | streamed kt11..15 ----
        // Producer of A-fragment kt is wave kt>>1.
        auto LS = [&](int kt, f16x8(&bf)[4]) {
#pragma unroll
            for (int nt = 0; nt < 4; nt++)
                bf[nt] = *(const f16x8*)(wbase + ((size_t)kt * NTG + nt) * 512);
        };
        auto PK = [&](int kt) {
            f16x8 a = load_a(hb, LDH, kt, l15, l4);
#pragma unroll
            for (int nt = 0; nt < 4; nt++)
                acc[nt] = MFMA(a, wreg[kt][nt], acc[nt], 0, 0, 0);
        };
        auto CL = [&](int ktl) {
            f16x8 a = load_a(hb, LDH, PKT + ktl, l15, l4);
#pragma unroll
            for (int nt = 0; nt < 4; nt++)
                acc[nt] = MFMA(a, wlds[((size_t)ktl * NTG + ntg0 + nt) * 64 + lane],
                               acc[nt], 0, 0, 0);
        };
        auto CS = [&](int kt, f16x8(&bf)[4]) {
            f16x8 a = load_a(hb, LDH, kt, l15, l4);
#pragma unroll
            for (int nt = 0; nt < 4; nt++) acc[nt] = MFMA(a, bf[nt], acc[nt], 0, 0, 0);
        };

        // Schedule: all streams at >=6-position load-use distance; CLs
        // interleaved where streams would stall; spin before FIRST use of
        // each producer (full 8-producer coverage).
        /*pos0 */ spin(0, t); PK(0);
        /*pos1 */             PK(1);
        /*pos2 */ spin(5, t); CS(11, bA); LS(13, bA);
        /*pos3 */ spin(1, t); PK(2);
        /*pos4 */             PK(3);
        /*pos5 */ spin(6, t); CS(12, bB); LS(14, bB);
        /*pos6 */ spin(4, t); CL(0);
        /*pos7 */ spin(2, t); PK(4);
        /*pos8 */             CS(13, bA); LS(15, bA);
        /*pos9 */             PK(5);
        /*pos10*/             CL(1);
        /*pos11*/ spin(7, t); CS(14, bB); LS(11, bB);   // next-step kt11
        /*pos12*/ spin(3, t); PK(6);
        /*pos13*/             CL(2);
        /*pos14*/             CS(15, bA); LS(12, bA);   // next-step kt12
        /*pos15*/             PK(7);

        // h_new = tanh(acc [+ xproj]). Permuted column map: value (nt, slot
        // l15, row-slot r) -> true col w*64 + nt + 4*l15, so for fixed r the
        // 4 nt values are CONTIGUOUS -> one ds_write_b64 per r (4 total).
#pragma unroll
        for (int r = 0; r < 4; r++) {
            f16x4 hv;
#pragma unroll
            for (int nt = 0; nt < 4; nt++) {
                float v = acc[nt][r];
                if constexpr (XP == 1) v += xr32[nt][r];
                else if constexpr (XP == 2) v += (float)xr16[nt][r];
                hv[nt] = (f16)fast_tanh(v);
            }
            *(f16x4*)&hw[(l4 * 4 + r) * LDH + w * 64 + 4 * l15] = hv;
        }
        if constexpr (XP != 0) {
            if (lane == 0)
                __hip_atomic_store(&pflag[w], t + 1, __ATOMIC_RELEASE, WGSCOPE);
        } else {
            __syncthreads();
        }
    };

    f16* r0 = &hbuf[0][0][0];
    f16* r1 = &hbuf[1][0][0];
    f16* r2 = &hbuf[2][0][0];
    for (u32 t = 0; t < T; t += 2) {
        body(t,     r0, r1, sA, sB, 0);  // exit: sB=kt11', sA=kt12'
        body(t + 1, r1, r2, sB, sA, 1);  // exit: sA=kt11'', sB=kt12''
        f16* n0 = r2; f16* n1 = r0; f16* n2 = r1;  // 3-ring rotate by 2
        r0 = n0; r1 = n1; r2 = n2;
    }
    // after loop h_T sits in r0 (T even)

    // wait for all waves' h_T, then out = h_T @ Wph + bp
    if constexpr (XP != 0) {
        __builtin_amdgcn_s_setprio(0);
        for (;;) {
            u32 f = __hip_atomic_load(&pflag[lane & 7], __ATOMIC_ACQUIRE, WGSCOPE);
            if (((u32)__ballot(f >= (u32)T) & 0xffu) == 0xffu) break;
            __builtin_amdgcn_s_sleep(1);
        }
        __builtin_amdgcn_s_setprio(1);
    } else {
        __syncthreads();
    }
    {
        // Wph packed plain (perm=0); h in true-column order -> unchanged.
        float bpv = bp[w * 16 + l15];
        f32x4 acc = {bpv, bpv, bpv, bpv};
#pragma unroll 4
        for (int kt = 0; kt < H / 32; kt++) {
            f16x8 a = load_a(r0, LDH, kt, l15, l4);
            f16x8 b = *(const f16x8*)(Wph_p + (((size_t)kt * (C / 16) + w) * 64 + lane) * 8);
            acc = MFMA(a, b, acc, 0, 0, 0);
        }
#pragma unroll
        for (int r = 0; r < 4; r++)
            out[(size_t)(b0 + l4 * 4 + r) * C + w * 16 + l15] = acc[r];
    }
}

extern "C" void kernel_launch(void* const* d_in, const int* in_sizes, int n_in,
                              void* d_out, int out_size, void* d_ws, size_t ws_size,
                              hipStream_t stream) {
    const float* x   = (const float*)d_in[0];
    const float* Whx = (const float*)d_in[1];
    const float* Whh = (const float*)d_in[2];
    const float* Wph = (const float*)d_in[3];
    const float* bh  = (const float*)d_in[4];
    const float* bp  = (const float*)d_in[5];

    f16* wp = (f16*)d_ws; // 768 KB packed fp16 weights
    pack_w<<<dim3(128), 256, 0, stream>>>(Whx, D, H, 1, wp);
    pack_w<<<dim3(512), 256, 0, stream>>>(Whh, H, H, 1, wp + D * H);
    pack_w<<<dim3(128), 256, 0, stream>>>(Wph, H, C, 0, wp + D * H + H * H);

    const size_t wbytes = (size_t)(D * H + H * H + H * C) * sizeof(f16); // 768 KB
    const size_t xpel   = (size_t)T * 16 * NTG * 256;                    // 67.1M elems

    if (ws_size >= wbytes + xpel * sizeof(float)) {        // 257 MB: f32 xproj
        float* xpb = (float*)((char*)d_ws + wbytes);
        xproj_k<float><<<dim3(16, T / 16), TPB, 0, stream>>>(x, wp, bh, xpb);
        rnn_main<1><<<dim3(Bsz / ROWS), TPB, 0, stream>>>(x, wp, xpb, bh, bp,
                                                          (float*)d_out);
    } else if (ws_size >= wbytes + xpel * sizeof(f16)) {   // 129 MB: f16 xproj
        f16* xpb = (f16*)((char*)d_ws + wbytes);
        xproj_k<f16><<<dim3(16, T / 16), TPB, 0, stream>>>(x, wp, bh, xpb);
        rnn_main<2><<<dim3(Bsz / ROWS), TPB, 0, stream>>>(x, wp, xpb, bh, bp,
                                                          (float*)d_out);
    } else {                                               // fallback: in-loop Whx
        rnn_main<0><<<dim3(Bsz / ROWS), TPB, 0, stream>>>(x, wp, nullptr, bh, bp,
                                                          (float*)d_out);
    }
}